// Round 18
// baseline (1299.419 us; speedup 1.0000x reference)
//
#include <hip/hip_runtime.h>
#include <hip/hip_bf16.h>

// PointDSC-like network. B=2, N=3000, C=128, H=1, L=6. FP32 I/O.
// Round 18: KSPLIT 16->12 (pacc 49->36.9 MB/layer, grid still 576 >= 2/CU),
// convert_w hoisted to one launch for all 6 layers. attn_mf9 (512,4) kept:
// r17 showed occupancy gain (21->30%) beats its ~28MB partial spill.
// Lessons: prefetch always spills (r10,r15); MFMA loses on 64-ch convs (r15);
// merging qkv sels would drop grid below CU count (r15 trap).

#define BB 2
#define NN 3000
#define CC 128
#define LAYERS 6
#define BN_EPS 1e-5f
#define ATT_SCALE 0.08838834764831845f  // 1/sqrt(128)
#define INV_CNT (1.f / (float)(BB * NN))

typedef _Float16 f16;
typedef _Float16 f16x8 __attribute__((ext_vector_type(8)));
typedef float f32x4 __attribute__((ext_vector_type(4)));

// ---------------- init embedding
__global__ void init_conv(const float* __restrict__ corr, const float* __restrict__ W,
                          const float* __restrict__ bias, float* __restrict__ x) {
  int idx = blockIdx.x * 256 + threadIdx.x;
  if (idx >= BB * CC * NN) return;
  int n = idx % NN;
  int c = (idx / NN) % CC;
  int b = idx / (NN * CC);
  const float* cp = corr + (b * NN + n) * 6;
  float acc = bias[c];
#pragma unroll
  for (int d = 0; d < 6; ++d) acc += W[c * 6 + d] * cp[d];
  x[idx] = acc;
}

// ---------------- all-layer weight pre-conversion: fp32 -> hi/lo f16 planes.
// Per layer (131072 f16): [pcn_h][pcn_l][q_h][q_l][k_h][k_l][v_h][v_l].
__global__ void convert_w_all(const float* __restrict__ pcnW, const float* __restrict__ qW,
                              const float* __restrict__ kW, const float* __restrict__ vW,
                              f16* __restrict__ WCV) {
  int t = blockIdx.x * 256 + threadIdx.x;
  if (t >= LAYERS * 4 * 16384) return;
  int layer = t / (4 * 16384);
  int rem = t & (4 * 16384 - 1);
  int sel = rem >> 14, j = rem & 16383;
  const float* src = ((sel == 0) ? pcnW : (sel == 1) ? qW : (sel == 2) ? kW : vW) +
                     layer * 16384;
  float v = src[j];
  f16 h = (f16)v;
  f16* dst = WCV + layer * 131072;
  dst[(sel * 2) * 16384 + j] = h;
  dst[(sel * 2 + 1) * 16384 + j] = (f16)(v - (float)h);
}

// ---------------- MFMA conv: pcn (128->128), pre-converted W, stats epilogue
__launch_bounds__(256)
__global__ void conv_mfma_pcn(const float* __restrict__ Xg, float* __restrict__ Y,
                              const f16* __restrict__ WCV, const float* __restrict__ bias,
                              float* __restrict__ osums) {
  __shared__ f16 Xsh[32][136], Xsl[32][136];
  __shared__ f16 Wsh[128][40], Wsl[128][40];
  const int tid = threadIdx.x;
  const int p0 = blockIdx.x * 32;
  const int w = tid >> 6, lane = tid & 63, quad = lane >> 4, l15 = lane & 15;
  const int co0 = w * 32;
  const f16* Wh = WCV;
  const f16* Wl = WCV + 16384;

  for (int idx = tid; idx < 512; idx += 256) {
    int ci = (idx >> 5) * 8, j = idx & 31;
    int p = p0 + j;
    if (p >= BB * NN) p = BB * NN - 1;
    int b = p / NN, n = p % NN;
    f16x8 hv, lv;
#pragma unroll
    for (int t = 0; t < 8; ++t) {
      float v = Xg[(b * 128 + ci + t) * NN + n];
      f16 h = (f16)v;
      hv[t] = h;
      lv[t] = (f16)(v - (float)h);
    }
    *reinterpret_cast<f16x8*>(&Xsh[j][ci]) = hv;
    *reinterpret_cast<f16x8*>(&Xsl[j][ci]) = lv;
  }

  f32x4 acc[2][2];
#pragma unroll
  for (int ct = 0; ct < 2; ++ct)
#pragma unroll
    for (int pt = 0; pt < 2; ++pt) acc[ct][pt] = (f32x4){0.f, 0.f, 0.f, 0.f};

  for (int kc = 0; kc < 4; ++kc) {
    __syncthreads();
    for (int idx = tid; idx < 512; idx += 256) {
      int co = idx >> 2, ks = idx & 3;
      int off = co * 128 + kc * 32 + ks * 8;
      *reinterpret_cast<uint4*>(&Wsh[co][ks * 8]) =
          *reinterpret_cast<const uint4*>(Wh + off);
      *reinterpret_cast<uint4*>(&Wsl[co][ks * 8]) =
          *reinterpret_cast<const uint4*>(Wl + off);
    }
    __syncthreads();
#pragma unroll
    for (int ct = 0; ct < 2; ++ct) {
      f16x8 ah = *reinterpret_cast<const f16x8*>(&Wsh[co0 + ct * 16 + l15][quad * 8]);
      f16x8 al = *reinterpret_cast<const f16x8*>(&Wsl[co0 + ct * 16 + l15][quad * 8]);
#pragma unroll
      for (int pt = 0; pt < 2; ++pt) {
        f16x8 bh = *reinterpret_cast<const f16x8*>(&Xsh[pt * 16 + l15][kc * 32 + quad * 8]);
        f16x8 bl = *reinterpret_cast<const f16x8*>(&Xsl[pt * 16 + l15][kc * 32 + quad * 8]);
        acc[ct][pt] = __builtin_amdgcn_mfma_f32_16x16x32_f16(ah, bl, acc[ct][pt], 0, 0, 0);
        acc[ct][pt] = __builtin_amdgcn_mfma_f32_16x16x32_f16(al, bh, acc[ct][pt], 0, 0, 0);
        acc[ct][pt] = __builtin_amdgcn_mfma_f32_16x16x32_f16(ah, bh, acc[ct][pt], 0, 0, 0);
      }
    }
  }

  float sp[2][4] = {{0.f}}, sp2[2][4] = {{0.f}};
#pragma unroll
  for (int ct = 0; ct < 2; ++ct)
#pragma unroll
    for (int pt = 0; pt < 2; ++pt) {
      int p = p0 + pt * 16 + l15;
      if (p < BB * NN) {
        int b = p / NN, n = p % NN;
#pragma unroll
        for (int r = 0; r < 4; ++r) {
          int co = co0 + ct * 16 + quad * 4 + r;
          float v = acc[ct][pt][r] + bias[co];
          Y[(b * 128 + co) * NN + n] = v;
          sp[ct][r] += v;
          sp2[ct][r] += v * v;
        }
      }
    }
#pragma unroll
  for (int ct = 0; ct < 2; ++ct)
#pragma unroll
    for (int r = 0; r < 4; ++r)
#pragma unroll
      for (int d = 1; d <= 8; d <<= 1) {
        sp[ct][r] += __shfl_xor(sp[ct][r], d);
        sp2[ct][r] += __shfl_xor(sp2[ct][r], d);
      }
  if (l15 == 0) {
#pragma unroll
    for (int ct = 0; ct < 2; ++ct)
#pragma unroll
      for (int r = 0; r < 4; ++r) {
        int co = co0 + ct * 16 + quad * 4 + r;
        atomicAdd(&osums[co], sp[ct][r]);
        atomicAdd(&osums[128 + co], sp2[ct][r]);
      }
  }
}

// ---------------- MFMA conv: QKV, pre-converted W, bn+relu input
__launch_bounds__(256)
__global__ void conv_mfma_qkv(const float* __restrict__ Yp, const float* __restrict__ psums,
                              const float* __restrict__ pg, const float* __restrict__ pbeta,
                              const f16* __restrict__ WCV,
                              const float* __restrict__ qb, const float* __restrict__ kb,
                              const float* __restrict__ vb,
                              f16* __restrict__ Qh, f16* __restrict__ Ql,
                              f16* __restrict__ Kh, f16* __restrict__ Kl,
                              f16* __restrict__ Vh, f16* __restrict__ Vl) {
  __shared__ f16 Xsh[32][136], Xsl[32][136];
  __shared__ f16 Wsh[128][40], Wsl[128][40];
  __shared__ float bnsc[128], bnsh[128];
  const int tid = threadIdx.x;
  const int p0 = blockIdx.x * 32;
  const int sel = blockIdx.y;
  const int w = tid >> 6, lane = tid & 63, quad = lane >> 4, l15 = lane & 15;
  const int co0 = w * 32;
  const f16* Wh = WCV + (2 + sel * 2) * 16384;
  const f16* Wl = Wh + 16384;
  const float* bias = (sel == 0) ? qb : (sel == 1) ? kb : vb;

  for (int c = tid; c < 128; c += 256) {
    float s = psums[c], s2 = psums[128 + c];
    float mean = s * INV_CNT;
    float var = s2 * INV_CNT - mean * mean;
    float sc = pg[c] * rsqrtf(var + BN_EPS);
    bnsc[c] = sc;
    bnsh[c] = pbeta[c] - mean * sc;
  }
  __syncthreads();

  for (int idx = tid; idx < 512; idx += 256) {
    int ci = (idx >> 5) * 8, j = idx & 31;
    int p = p0 + j;
    if (p >= BB * NN) p = BB * NN - 1;
    int b = p / NN, n = p % NN;
    f16x8 hv, lv;
#pragma unroll
    for (int t = 0; t < 8; ++t) {
      float v = Yp[(b * 128 + ci + t) * NN + n];
      v = v * bnsc[ci + t] + bnsh[ci + t];
      v = v > 0.f ? v : 0.f;
      f16 h = (f16)v;
      hv[t] = h;
      lv[t] = (f16)(v - (float)h);
    }
    *reinterpret_cast<f16x8*>(&Xsh[j][ci]) = hv;
    *reinterpret_cast<f16x8*>(&Xsl[j][ci]) = lv;
  }

  f32x4 acc[2][2];
#pragma unroll
  for (int ct = 0; ct < 2; ++ct)
#pragma unroll
    for (int pt = 0; pt < 2; ++pt) acc[ct][pt] = (f32x4){0.f, 0.f, 0.f, 0.f};

  for (int kc = 0; kc < 4; ++kc) {
    __syncthreads();
    for (int idx = tid; idx < 512; idx += 256) {
      int co = idx >> 2, ks = idx & 3;
      int off = co * 128 + kc * 32 + ks * 8;
      *reinterpret_cast<uint4*>(&Wsh[co][ks * 8]) =
          *reinterpret_cast<const uint4*>(Wh + off);
      *reinterpret_cast<uint4*>(&Wsl[co][ks * 8]) =
          *reinterpret_cast<const uint4*>(Wl + off);
    }
    __syncthreads();
#pragma unroll
    for (int ct = 0; ct < 2; ++ct) {
      f16x8 ah = *reinterpret_cast<const f16x8*>(&Wsh[co0 + ct * 16 + l15][quad * 8]);
      f16x8 al = *reinterpret_cast<const f16x8*>(&Wsl[co0 + ct * 16 + l15][quad * 8]);
#pragma unroll
      for (int pt = 0; pt < 2; ++pt) {
        f16x8 bh = *reinterpret_cast<const f16x8*>(&Xsh[pt * 16 + l15][kc * 32 + quad * 8]);
        f16x8 bl = *reinterpret_cast<const f16x8*>(&Xsl[pt * 16 + l15][kc * 32 + quad * 8]);
        acc[ct][pt] = __builtin_amdgcn_mfma_f32_16x16x32_f16(ah, bl, acc[ct][pt], 0, 0, 0);
        acc[ct][pt] = __builtin_amdgcn_mfma_f32_16x16x32_f16(al, bh, acc[ct][pt], 0, 0, 0);
        acc[ct][pt] = __builtin_amdgcn_mfma_f32_16x16x32_f16(ah, bh, acc[ct][pt], 0, 0, 0);
      }
    }
  }

#pragma unroll
  for (int ct = 0; ct < 2; ++ct)
#pragma unroll
    for (int pt = 0; pt < 2; ++pt) {
      int p = p0 + pt * 16 + l15;
      if (p < BB * NN) {
        int b = p / NN, n = p % NN;
#pragma unroll
        for (int r = 0; r < 4; ++r) {
          int co = co0 + ct * 16 + quad * 4 + r;
          float v = acc[ct][pt][r] + bias[co];
          f16 h = (f16)v;
          f16 lo = (f16)(v - (float)h);
          if (sel == 0) {
            size_t o = (size_t)(b * NN + n) * CC + co;
            Qh[o] = h; Ql[o] = lo;
          } else if (sel == 1) {
            size_t o = (size_t)(b * NN + n) * CC + co;
            Kh[o] = h; Kl[o] = lo;
          } else {
            size_t o = (size_t)(b * CC + co) * NN + n;
            Vh[o] = h; Vl[o] = lo;
          }
        }
      }
    }
}

// ---------------- generic VALU conv (r14 proven), NP points per block.
template <int CIN, int COUT, int NP, int MODE, int CSPLIT, int BNIN, int STATS>
__launch_bounds__(256)
__global__ void conv_k(const float* __restrict__ in, float* __restrict__ out,
                       const float* __restrict__ W, const float* __restrict__ bias,
                       const float* __restrict__ res,
                       const float* __restrict__ isums, const float* __restrict__ ig,
                       const float* __restrict__ ibeta,
                       const float* __restrict__ rsums, const float* __restrict__ rg,
                       const float* __restrict__ rbeta, float* __restrict__ osums) {
  constexpr int COB = COUT / CSPLIT;
  constexpr int CH = (CIN > 64) ? 64 : CIN;
  constexpr int PG = NP / 4;
  constexpr int KPT = COB * PG / 256;
  constexpr int XROW = (NP == 16) ? 20 : 32;
  __shared__ alignas(16) float Xs[CIN][XROW];
  __shared__ float Ws[COB][CH + 1];
  __shared__ float bnsc[BNIN ? CIN : 1], bnsh[BNIN ? CIN : 1];
  const int tid = threadIdx.x;
  const int p0 = blockIdx.x * NP;
  const int co0 = blockIdx.y * COB;

  if (BNIN) {
    for (int c = tid; c < CIN; c += 256) {
      float s = isums[c], s2 = isums[CIN + c];
      float mean = s * INV_CNT;
      float var = s2 * INV_CNT - mean * mean;
      float sc = ig[c] * rsqrtf(var + BN_EPS);
      bnsc[c] = sc;
      bnsh[c] = ibeta[c] - mean * sc;
    }
    __syncthreads();
  }

  for (int idx = tid; idx < CIN * NP; idx += 256) {
    int ci = idx / NP, j = idx % NP;
    int p = p0 + j;
    float v = 0.f;
    if (p < BB * NN) {
      int b = p / NN, n = p % NN;
      v = in[(b * CIN + ci) * NN + n];
      if (BNIN) {
        v = v * bnsc[ci] + bnsh[ci];
        v = v > 0.f ? v : 0.f;
      }
    }
    Xs[ci][j] = v;
  }

  const int nb = (tid % PG) * 4;
  const int cb = (tid / PG) * KPT;

  float acc[KPT][4];
#pragma unroll
  for (int k = 0; k < KPT; ++k)
#pragma unroll
    for (int j = 0; j < 4; ++j) acc[k][j] = 0.f;

  for (int c0 = 0; c0 < CIN; c0 += CH) {
    __syncthreads();
    for (int idx = tid; idx < COB * CH; idx += 256) {
      int co = idx / CH, cc = idx % CH;
      Ws[co][cc] = W[(co0 + co) * CIN + c0 + cc];
    }
    __syncthreads();
#pragma unroll 4
    for (int cc = 0; cc < CH; ++cc) {
      float4 xv = *reinterpret_cast<const float4*>(&Xs[c0 + cc][nb]);
#pragma unroll
      for (int k = 0; k < KPT; ++k) {
        float w = Ws[cb + k][cc];
        acc[k][0] += w * xv.x;
        acc[k][1] += w * xv.y;
        acc[k][2] += w * xv.z;
        acc[k][3] += w * xv.w;
      }
    }
  }

#pragma unroll
  for (int k = 0; k < KPT; ++k) {
    int co = co0 + cb + k;
    float bv = bias[co];
    float rsc = 0.f, rsh = 0.f;
    if (MODE == 3) {
      float s = rsums[co], s2 = rsums[COUT + co];
      float mean = s * INV_CNT;
      float var = s2 * INV_CNT - mean * mean;
      rsc = rg[co] * rsqrtf(var + BN_EPS);
      rsh = rbeta[co] - mean * rsc;
    }
    float sp = 0.f, sp2 = 0.f;
#pragma unroll
    for (int j = 0; j < 4; ++j) {
      int p = p0 + nb + j;
      if (p < BB * NN) {
        int b = p / NN, n = p % NN;
        int o = (b * COUT + co) * NN + n;
        float v = acc[k][j] + bv;
        if (MODE == 3) {
          float rr = res[o] * rsc + rsh;
          v += (rr > 0.f ? rr : 0.f);
        }
        out[o] = v;
        if (STATS) {
          sp += v;
          sp2 += v * v;
        }
      }
    }
    if (STATS) {
#pragma unroll
      for (int d = 1; d < PG; d <<= 1) {
        sp += __shfl_xor(sp, d);
        sp2 += __shfl_xor(sp2, d);
      }
      if ((tid & (PG - 1)) == 0) {
        atomicAdd(&osums[co], sp);
        atomicAdd(&osums[COUT + co], sp2);
      }
    }
  }
}

// ---------------- full-MFMA attention: 128 q/block, qp in LDS, 2 blocks/CU (r17)
__launch_bounds__(512, 4)
__global__ void attn_mf9(const f16* __restrict__ Qhp, const f16* __restrict__ Qlp,
                         const f16* __restrict__ Khp, const f16* __restrict__ Klp,
                         const f16* __restrict__ Vhp, const f16* __restrict__ Vlp,
                         const float* __restrict__ srcp, const float* __restrict__ tgtp,
                         float* __restrict__ pacc, float* __restrict__ pm,
                         float* __restrict__ pl, int chunk) {
  const int b = blockIdx.z;
  const int q0 = blockIdx.x * 128;
  const int s = blockIdx.y;
  const int cs = s * chunk;
  const int ce = min(cs + chunk, NN);
  const int tid = threadIdx.x;
  const int w = tid >> 6, lane = tid & 63, quad = lane >> 4, l15 = lane & 15;

  __shared__ f16 Ksh[32][136], Ksl[32][136];
  __shared__ f16 Vsh[128][40], Vsl[128][40];
  __shared__ f16 Ps[8][16][40];
  __shared__ float kps[6][36];
  __shared__ float qps[8][16][6];

  for (int t = tid; t < 768; t += 512) {
    int w2 = t / 96, rem = t % 96, row = rem / 6, d = rem % 6;
    int o = q0 + w2 * 16 + row;
    if (o >= NN) o = NN - 1;
    qps[w2][row][d] = (d < 3) ? srcp[(b * NN + o) * 3 + d] : tgtp[(b * NN + o) * 3 + d - 3];
  }

  f16x8 qh[4], ql[4];
  const int orow = q0 + w * 16;
  {
    int o = orow + l15;
    if (o >= NN) o = NN - 1;
    size_t base = (size_t)(b * NN + o) * CC + quad * 8;
#pragma unroll
    for (int cc = 0; cc < 4; ++cc) {
      qh[cc] = *reinterpret_cast<const f16x8*>(Qhp + base + cc * 32);
      ql[cc] = *reinterpret_cast<const f16x8*>(Qlp + base + cc * 32);
    }
  }

  float m[4], l[4];
#pragma unroll
  for (int r = 0; r < 4; ++r) {
    m[r] = -1e30f;
    l[r] = 0.f;
  }
  f32x4 acco[8];
#pragma unroll
  for (int t = 0; t < 8; ++t) acco[t] = (f32x4){0.f, 0.f, 0.f, 0.f};

  const int NT = (ce - cs + 31) >> 5;
  for (int it = 0; it < NT; ++it) {
    const int kk0 = cs + it * 32;
    __syncthreads();
    for (int t = tid; t < 1024; t += 512) {
      int plane = t >> 9, row = (t >> 4) & 31, cu = t & 15;
      int kr = kk0 + row;
      if (kr >= NN) kr = NN - 1;
      const f16* src = (plane ? Klp : Khp) + (size_t)(b * NN + kr) * CC + cu * 8;
      uint4 v = *reinterpret_cast<const uint4*>(src);
      f16* dst = plane ? &Ksl[row][cu * 8] : &Ksh[row][cu * 8];
      *reinterpret_cast<uint4*>(dst) = v;
    }
    for (int t = tid; t < 1024; t += 512) {
      int plane = t >> 9, c = (t >> 2) & 127, iu = t & 3;
      int kb = kk0 + iu * 8;
      if (kb > NN - 8) kb = NN - 8;
      const f16* src = (plane ? Vlp : Vhp) + (size_t)(b * CC + c) * NN + kb;
      uint4 v = *reinterpret_cast<const uint4*>(src);
      f16* dst = plane ? &Vsl[c][iu * 8] : &Vsh[c][iu * 8];
      *reinterpret_cast<uint4*>(dst) = v;
    }
    if (tid < 192) {
      int d = tid >> 5, i = tid & 31;
      int ig = kk0 + i;
      if (ig >= NN) ig = NN - 1;
      kps[d][i] = (d < 3) ? srcp[(b * NN + ig) * 3 + d] : tgtp[(b * NN + ig) * 3 + d - 3];
    }
    __syncthreads();

    f32x4 accs[2];
#pragma unroll
    for (int k4 = 0; k4 < 2; ++k4) accs[k4] = (f32x4){0.f, 0.f, 0.f, 0.f};
#pragma unroll
    for (int cc = 0; cc < 4; ++cc) {
#pragma unroll
      for (int k4 = 0; k4 < 2; ++k4) {
        f16x8 bh = *reinterpret_cast<const f16x8*>(&Ksh[k4 * 16 + l15][cc * 32 + quad * 8]);
        f16x8 bl = *reinterpret_cast<const f16x8*>(&Ksl[k4 * 16 + l15][cc * 32 + quad * 8]);
        accs[k4] = __builtin_amdgcn_mfma_f32_16x16x32_f16(qh[cc], bl, accs[k4], 0, 0, 0);
        accs[k4] = __builtin_amdgcn_mfma_f32_16x16x32_f16(ql[cc], bh, accs[k4], 0, 0, 0);
        accs[k4] = __builtin_amdgcn_mfma_f32_16x16x32_f16(qh[cc], bh, accs[k4], 0, 0, 0);
      }
    }

    float sv[2][4];
#pragma unroll
    for (int r = 0; r < 4; ++r) {
      const float* qp6 = qps[w][quad * 4 + r];
      float q0v = qp6[0], q1v = qp6[1], q2v = qp6[2];
      float q3v = qp6[3], q4v = qp6[4], q5v = qp6[5];
#pragma unroll
      for (int k4 = 0; k4 < 2; ++k4) {
        int iloc = k4 * 16 + l15;
        int ig = kk0 + iloc;
        float dx = q0v - kps[0][iloc], dy = q1v - kps[1][iloc], dz = q2v - kps[2][iloc];
        float ds2 = dx * dx + dy * dy + dz * dz;
        float ex = q3v - kps[3][iloc], ey = q4v - kps[4][iloc], ez = q5v - kps[5][iloc];
        float dt2 = ex * ex + ey * ey + ez * ez;
        float d2 = ds2 + dt2 - 2.f * sqrtf(ds2 * dt2);
        float gg = 1.f - d2;
        gg = gg > 0.f ? gg : 0.f;
        float val = accs[k4][r] * (ATT_SCALE * gg);
        sv[k4][r] = (ig < ce) ? val : -1e30f;
      }
    }

    float tmax[4];
#pragma unroll
    for (int r = 0; r < 4; ++r) tmax[r] = fmaxf(sv[0][r], sv[1][r]);
#pragma unroll
    for (int d = 1; d <= 8; d <<= 1)
#pragma unroll
      for (int r = 0; r < 4; ++r) tmax[r] = fmaxf(tmax[r], __shfl_xor(tmax[r], d));

    float alpha[4], ps[4];
    f16 pf[2][4];
#pragma unroll
    for (int r = 0; r < 4; ++r) {
      float mn = fmaxf(m[r], tmax[r]);
      alpha[r] = __expf(m[r] - mn);
      m[r] = mn;
      pf[0][r] = (f16)__expf(sv[0][r] - mn);
      pf[1][r] = (f16)__expf(sv[1][r] - mn);
      ps[r] = (float)pf[0][r] + (float)pf[1][r];
    }
#pragma unroll
    for (int d = 1; d <= 8; d <<= 1)
#pragma unroll
      for (int r = 0; r < 4; ++r) ps[r] += __shfl_xor(ps[r], d);
#pragma unroll
    for (int r = 0; r < 4; ++r) {
      l[r] = l[r] * alpha[r] + ps[r];
#pragma unroll
      for (int t = 0; t < 8; ++t) acco[t][r] *= alpha[r];
    }
#pragma unroll
    for (int r = 0; r < 4; ++r) {
      Ps[w][quad * 4 + r][l15] = pf[0][r];
      Ps[w][quad * 4 + r][16 + l15] = pf[1][r];
    }
    __syncthreads();

    {
      f16x8 af = *reinterpret_cast<const f16x8*>(&Ps[w][l15][quad * 8]);
#pragma unroll
      for (int t = 0; t < 8; ++t) {
        f16x8 vh = *reinterpret_cast<const f16x8*>(&Vsh[t * 16 + l15][quad * 8]);
        f16x8 vl = *reinterpret_cast<const f16x8*>(&Vsl[t * 16 + l15][quad * 8]);
        acco[t] = __builtin_amdgcn_mfma_f32_16x16x32_f16(af, vl, acco[t], 0, 0, 0);
        acco[t] = __builtin_amdgcn_mfma_f32_16x16x32_f16(af, vh, acco[t], 0, 0, 0);
      }
    }
  }

  const int pidx = s * BB + b;
  if (l15 == 0) {
#pragma unroll
    for (int r = 0; r < 4; ++r) {
      int o = orow + quad * 4 + r;
      if (o < NN) {
        pm[pidx * NN + o] = m[r];
        pl[pidx * NN + o] = l[r];
      }
    }
  }
#pragma unroll
  for (int r = 0; r < 4; ++r) {
    int o = orow + quad * 4 + r;
    if (o < NN) {
      size_t base2 = ((size_t)pidx * NN + o) * CC;
#pragma unroll
      for (int t = 0; t < 8; ++t) pacc[base2 + t * 16 + l15] = acco[t][r];
    }
  }
}

// ---------------- m1 conv (16-pt tiles) with fused K-split combine + stats (r14)
__launch_bounds__(256)
__global__ void conv_m1(const float* __restrict__ pacc, const float* __restrict__ pm,
                        const float* __restrict__ pl, float* __restrict__ out,
                        const float* __restrict__ W, const float* __restrict__ bias,
                        float* __restrict__ osums, int ksplit) {
  __shared__ alignas(16) float Xs[128][20];
  __shared__ float Ws[64][65];
  __shared__ float Es[16][17];
  __shared__ float Li[16];
  const int tid = threadIdx.x;
  const int p0 = blockIdx.x * 16;

  if (tid < 16) {
    int p = p0 + tid;
    float Lv = 1.f;
    if (p < BB * NN) {
      int b = p / NN, o = p % NN;
      float M = -1e30f;
      for (int s = 0; s < ksplit; ++s) M = fmaxf(M, pm[(s * BB + b) * NN + o]);
      Lv = 0.f;
      for (int s = 0; s < ksplit; ++s) {
        int pi = s * BB + b;
        float e = __expf(pm[pi * NN + o] - M);
        Es[tid][s] = e;
        Lv += pl[pi * NN + o] * e;
      }
    } else {
      for (int s = 0; s < ksplit; ++s) Es[tid][s] = 0.f;
    }
    Li[tid] = 1.f / Lv;
  }
  __syncthreads();

  for (int idx = tid; idx < 512; idx += 256) {
    int j = idx >> 5, c4 = (idx & 31) * 4;
    int p = p0 + j;
    float4 a = {0.f, 0.f, 0.f, 0.f};
    if (p < BB * NN) {
      int b = p / NN, o = p % NN;
      for (int s = 0; s < ksplit; ++s) {
        float e = Es[j][s];
        const float4 pv = *reinterpret_cast<const float4*>(
            &pacc[((size_t)(s * BB + b) * NN + o) * CC + c4]);
        a.x += pv.x * e;
        a.y += pv.y * e;
        a.z += pv.z * e;
        a.w += pv.w * e;
      }
      float inv = Li[j];
      a.x *= inv; a.y *= inv; a.z *= inv; a.w *= inv;
    }
    Xs[c4][j] = a.x;
    Xs[c4 + 1][j] = a.y;
    Xs[c4 + 2][j] = a.z;
    Xs[c4 + 3][j] = a.w;
  }

  const int nb = (tid & 3) * 4;
  const int co = tid >> 2;
  float acc[4] = {0.f, 0.f, 0.f, 0.f};

  for (int c0 = 0; c0 < 128; c0 += 64) {
    __syncthreads();
    for (int idx = tid; idx < 64 * 64; idx += 256) {
      int cr = idx >> 6, cc = idx & 63;
      Ws[cr][cc] = W[cr * 128 + c0 + cc];
    }
    __syncthreads();
#pragma unroll 4
    for (int cc = 0; cc < 64; ++cc) {
      float4 xv = *reinterpret_cast<const float4*>(&Xs[c0 + cc][nb]);
      float w = Ws[co][cc];
      acc[0] += w * xv.x;
      acc[1] += w * xv.y;
      acc[2] += w * xv.z;
      acc[3] += w * xv.w;
    }
  }

  {
    float bv = bias[co];
    float sp = 0.f, sp2 = 0.f;
#pragma unroll
    for (int j = 0; j < 4; ++j) {
      int p = p0 + nb + j;
      if (p < BB * NN) {
        int b = p / NN, n = p % NN;
        float v = acc[j] + bv;
        out[(b * 64 + co) * NN + n] = v;
        sp += v;
        sp2 += v * v;
      }
    }
    sp += __shfl_xor(sp, 1);
    sp2 += __shfl_xor(sp2, 1);
    sp += __shfl_xor(sp, 2);
    sp2 += __shfl_xor(sp2, 2);
    if ((tid & 3) == 0) {
      atomicAdd(&osums[co], sp);
      atomicAdd(&osums[64 + co], sp2);
    }
  }
}

// ---------------- fused head (proven)
__launch_bounds__(256)
__global__ void head_all(const float* __restrict__ Xg,
                         const float* __restrict__ c1W, const float* __restrict__ c1b,
                         const float* __restrict__ c2W, const float* __restrict__ c2b,
                         const float* __restrict__ c3W, const float* __restrict__ c3b,
                         float* __restrict__ out) {
  __shared__ float Xs[128][33];
  __shared__ float W1[32][129];
  __shared__ float W2[32][33];
  __shared__ float Hs[32][33], H2s[32][33];
  __shared__ float Inv[32];
  const int tid = threadIdx.x;
  const int p0 = blockIdx.x * 32;
  const int j = tid >> 3, sub = tid & 7;

  for (int idx = tid; idx < 128 * 32; idx += 256) {
    int ci = idx >> 5, jj = idx & 31;
    int p = p0 + jj;
    float v = 0.f;
    if (p < BB * NN) {
      int b = p / NN, n = p % NN;
      v = Xg[(b * 128 + ci) * NN + n];
    }
    Xs[ci][jj] = v;
  }
  for (int idx = tid; idx < 32 * 128; idx += 256) {
    W1[idx >> 7][idx & 127] = c1W[idx];
  }
  for (int idx = tid; idx < 32 * 32; idx += 256) {
    W2[idx >> 5][idx & 31] = c2W[idx];
  }
  __syncthreads();

  {
    float h1v[4];
#pragma unroll
    for (int k = 0; k < 4; ++k) h1v[k] = c1b[sub * 4 + k];
    for (int ci = 0; ci < 128; ++ci) {
      float xv = Xs[ci][j];
#pragma unroll
      for (int k = 0; k < 4; ++k) h1v[k] += W1[sub * 4 + k][ci] * xv;
    }
#pragma unroll
    for (int k = 0; k < 4; ++k) Hs[j][sub * 4 + k] = h1v[k] > 0.f ? h1v[k] : 0.f;
  }
  __syncthreads();
  {
    float h2v[4];
#pragma unroll
    for (int k = 0; k < 4; ++k) h2v[k] = c2b[sub * 4 + k];
#pragma unroll
    for (int cc = 0; cc < 32; ++cc) {
      float hv = Hs[j][cc];
#pragma unroll
      for (int k = 0; k < 4; ++k) h2v[k] += W2[sub * 4 + k][cc] * hv;
    }
#pragma unroll
    for (int k = 0; k < 4; ++k) H2s[j][sub * 4 + k] = h2v[k] > 0.f ? h2v[k] : 0.f;
  }
  __syncthreads();

  float ssp = 0.f;
#pragma unroll
  for (int k = 0; k < 16; ++k) {
    float v = Xs[sub + 8 * k][j];
    ssp += v * v;
  }
  ssp += __shfl_xor(ssp, 1);
  ssp += __shfl_xor(ssp, 2);
  ssp += __shfl_xor(ssp, 4);

  if (sub == 0) {
    int p = p0 + j;
    if (p < BB * NN) {
      float conf = c3b[0];
#pragma unroll
      for (int c = 0; c < 32; ++c) conf += c3W[c] * H2s[j][c];
      out[p] = conf;
    }
    float nrm = sqrtf(ssp);
    nrm = nrm > 1e-12f ? nrm : 1e-12f;
    Inv[j] = 1.f / nrm;
  }
  __syncthreads();

  for (int idx = tid; idx < 128 * 32; idx += 256) {
    int c = idx >> 5, jj = idx & 31;
    int p = p0 + jj;
    if (p < BB * NN) {
      int b = p / NN, n = p % NN;
      out[BB * NN + (b * 128 + c) * NN + n] = Xs[c][jj] * Inv[jj];
    }
  }
}

extern "C" void kernel_launch(void* const* d_in, const int* in_sizes, int n_in,
                              void* d_out, int out_size, void* d_ws, size_t ws_size,
                              hipStream_t stream) {
  const float* corr = (const float*)d_in[0];
  const float* srcp = (const float*)d_in[1];
  const float* tgtp = (const float*)d_in[2];
  const float* initW = (const float*)d_in[3];
  const float* initb = (const float*)d_in[4];
  const float* pcnW = (const float*)d_in[5];
  const float* pcnb = (const float*)d_in[6];
  const float* pcng = (const float*)d_in[7];
  const float* pcnbeta = (const float*)d_in[8];
  const float* qW = (const float*)d_in[9];
  const float* qb = (const float*)d_in[10];
  const float* kW = (const float*)d_in[11];
  const float* kb = (const float*)d_in[12];
  const float* vW = (const float*)d_in[13];
  const float* vb = (const float*)d_in[14];
  const float* m1W = (const float*)d_in[15];
  const float* m1b = (const float*)d_in[16];
  const float* m1g = (const float*)d_in[17];
  const float* m1beta = (const float*)d_in[18];
  const float* m2W = (const float*)d_in[19];
  const float* m2b = (const float*)d_in[20];
  const float* m2g = (const float*)d_in[21];
  const float* m2beta = (const float*)d_in[22];
  const float* m3W = (const float*)d_in[23];
  const float* m3b = (const float*)d_in[24];
  const float* c1W = (const float*)d_in[25];
  const float* c1b = (const float*)d_in[26];
  const float* c2W = (const float*)d_in[27];
  const float* c2b = (const float*)d_in[28];
  const float* c3W = (const float*)d_in[29];
  const float* c3b = (const float*)d_in[30];

  const int FEAT = BB * CC * NN;   // 768000
  const int PLANE = FEAT / 2;
  float* ws = (float*)d_ws;
  float* X = ws;
  float* Y = X + FEAT;
  float* QhF = Y + FEAT;
  float* QlF = QhF + PLANE;
  float* KhF = QlF + PLANE;
  float* KlF = KhF + PLANE;
  float* VhF = KlF + PLANE;
  float* VlF = VhF + PLANE;
  float* SB = VlF + PLANE;            // stats (3072 floats)
  float* WCVf = SB + 3072;            // all-layer weight planes (393216 floats)
  float* pacc = WCVf + LAYERS * 65536;
  f16* Qh = (f16*)QhF;
  f16* Ql = (f16*)QlF;
  f16* Kh = (f16*)KhF;
  f16* Kl = (f16*)KlF;
  f16* Vh = (f16*)VhF;
  f16* Vl = (f16*)VlF;
  f16* WCV = (f16*)WCVf;
  float* T1 = QhF;
  float* T2 = KhF;

  const size_t base_f = (size_t)(2 * FEAT + 6 * PLANE + 3072 + LAYERS * 65536);
  const size_t per_f = (size_t)BB * NN * CC + 2 * (size_t)BB * NN;
  int ksplit = 12;
  while (ksplit > 1 && (base_f + (size_t)ksplit * per_f) * 4 > ws_size) ksplit >>= 1;
  const int chunk = (((NN + ksplit - 1) / ksplit) + 7) & ~7;
  float* pm = pacc + (size_t)ksplit * BB * NN * CC;
  float* pl = pm + (size_t)ksplit * BB * NN;

  dim3 blk(256);
  const int PT32 = (BB * NN + 31) / 32;  // 188
  const int PT16 = (BB * NN + 15) / 16;  // 375
  const int G_FEAT = (FEAT + 255) / 256;

  hipMemsetAsync(SB, 0, 3072 * sizeof(float), stream);
  convert_w_all<<<(LAYERS * 4 * 16384 + 255) / 256, blk, 0, stream>>>(
      pcnW, qW, kW, vW, WCV);
  init_conv<<<G_FEAT, blk, 0, stream>>>(corr, initW, initb, X);

  for (int i = 0; i < LAYERS; ++i) {
    float* pcnS = SB + i * 512;
    float* m1S = pcnS + 256;
    float* m2S = m1S + 128;
    const f16* WL = WCV + (size_t)i * 131072;
    conv_mfma_pcn<<<PT32, blk, 0, stream>>>(X, Y, WL, pcnb + i * 128, pcnS);
    conv_mfma_qkv<<<dim3(PT32, 3), blk, 0, stream>>>(
        Y, pcnS, pcng + i * 128, pcnbeta + i * 128, WL,
        qb + i * 128, kb + i * 128, vb + i * 128, Qh, Ql, Kh, Kl, Vh, Vl);
    attn_mf9<<<dim3((NN + 127) / 128, ksplit, BB), dim3(512), 0, stream>>>(
        Qh, Ql, Kh, Kl, Vh, Vl, srcp, tgtp, pacc, pm, pl, chunk);
    conv_m1<<<PT16, blk, 0, stream>>>(pacc, pm, pl, T1, m1W + i * 8192, m1b + i * 64,
                                      m1S, ksplit);
    conv_k<64, 64, 16, 0, 1, 1, 1><<<dim3(PT16, 1), blk, 0, stream>>>(
        T1, T2, m2W + i * 4096, m2b + i * 64, nullptr,
        m1S, m1g + i * 64, m1beta + i * 64, nullptr, nullptr, nullptr, m2S);
    conv_k<64, 128, 16, 3, 2, 1, 0><<<dim3(PT16, 2), blk, 0, stream>>>(
        T2, X, m3W + i * 8192, m3b + i * 128, Y,
        m2S, m2g + i * 64, m2beta + i * 64, pcnS, pcng + i * 128, pcnbeta + i * 128,
        nullptr);
  }

  head_all<<<PT32, blk, 0, stream>>>(X, c1W, c1b, c2W, c2b, c3W, c3b, (float*)d_out);
}

// Round 19
// 1243.846 us; speedup vs baseline: 1.0447x; 1.0447x over previous
//
#include <hip/hip_runtime.h>
#include <hip/hip_bf16.h>

// PointDSC-like network. B=2, N=3000, C=128, H=1, L=6. FP32 I/O.
// Round 19: best-known r17 attention restored (KSPLIT=16: grid 768 = 1.5
// full 512-block waves; r18's KSPLIT=12 gave a 512+64 tail => regression),
// keeping r18's hoisted convert_w_all. Lessons: prefetch always spills
// (r10,r15); MFMA loses on 64-ch convs (r15); grid must fill 512-block waves.

#define BB 2
#define NN 3000
#define CC 128
#define LAYERS 6
#define BN_EPS 1e-5f
#define ATT_SCALE 0.08838834764831845f  // 1/sqrt(128)
#define INV_CNT (1.f / (float)(BB * NN))

typedef _Float16 f16;
typedef _Float16 f16x8 __attribute__((ext_vector_type(8)));
typedef float f32x4 __attribute__((ext_vector_type(4)));

// ---------------- init embedding
__global__ void init_conv(const float* __restrict__ corr, const float* __restrict__ W,
                          const float* __restrict__ bias, float* __restrict__ x) {
  int idx = blockIdx.x * 256 + threadIdx.x;
  if (idx >= BB * CC * NN) return;
  int n = idx % NN;
  int c = (idx / NN) % CC;
  int b = idx / (NN * CC);
  const float* cp = corr + (b * NN + n) * 6;
  float acc = bias[c];
#pragma unroll
  for (int d = 0; d < 6; ++d) acc += W[c * 6 + d] * cp[d];
  x[idx] = acc;
}

// ---------------- all-layer weight pre-conversion: fp32 -> hi/lo f16 planes.
__global__ void convert_w_all(const float* __restrict__ pcnW, const float* __restrict__ qW,
                              const float* __restrict__ kW, const float* __restrict__ vW,
                              f16* __restrict__ WCV) {
  int t = blockIdx.x * 256 + threadIdx.x;
  if (t >= LAYERS * 4 * 16384) return;
  int layer = t / (4 * 16384);
  int rem = t & (4 * 16384 - 1);
  int sel = rem >> 14, j = rem & 16383;
  const float* src = ((sel == 0) ? pcnW : (sel == 1) ? qW : (sel == 2) ? kW : vW) +
                     layer * 16384;
  float v = src[j];
  f16 h = (f16)v;
  f16* dst = WCV + layer * 131072;
  dst[(sel * 2) * 16384 + j] = h;
  dst[(sel * 2 + 1) * 16384 + j] = (f16)(v - (float)h);
}

// ---------------- MFMA conv: pcn (128->128), pre-converted W, stats epilogue
__launch_bounds__(256)
__global__ void conv_mfma_pcn(const float* __restrict__ Xg, float* __restrict__ Y,
                              const f16* __restrict__ WCV, const float* __restrict__ bias,
                              float* __restrict__ osums) {
  __shared__ f16 Xsh[32][136], Xsl[32][136];
  __shared__ f16 Wsh[128][40], Wsl[128][40];
  const int tid = threadIdx.x;
  const int p0 = blockIdx.x * 32;
  const int w = tid >> 6, lane = tid & 63, quad = lane >> 4, l15 = lane & 15;
  const int co0 = w * 32;
  const f16* Wh = WCV;
  const f16* Wl = WCV + 16384;

  for (int idx = tid; idx < 512; idx += 256) {
    int ci = (idx >> 5) * 8, j = idx & 31;
    int p = p0 + j;
    if (p >= BB * NN) p = BB * NN - 1;
    int b = p / NN, n = p % NN;
    f16x8 hv, lv;
#pragma unroll
    for (int t = 0; t < 8; ++t) {
      float v = Xg[(b * 128 + ci + t) * NN + n];
      f16 h = (f16)v;
      hv[t] = h;
      lv[t] = (f16)(v - (float)h);
    }
    *reinterpret_cast<f16x8*>(&Xsh[j][ci]) = hv;
    *reinterpret_cast<f16x8*>(&Xsl[j][ci]) = lv;
  }

  f32x4 acc[2][2];
#pragma unroll
  for (int ct = 0; ct < 2; ++ct)
#pragma unroll
    for (int pt = 0; pt < 2; ++pt) acc[ct][pt] = (f32x4){0.f, 0.f, 0.f, 0.f};

  for (int kc = 0; kc < 4; ++kc) {
    __syncthreads();
    for (int idx = tid; idx < 512; idx += 256) {
      int co = idx >> 2, ks = idx & 3;
      int off = co * 128 + kc * 32 + ks * 8;
      *reinterpret_cast<uint4*>(&Wsh[co][ks * 8]) =
          *reinterpret_cast<const uint4*>(Wh + off);
      *reinterpret_cast<uint4*>(&Wsl[co][ks * 8]) =
          *reinterpret_cast<const uint4*>(Wl + off);
    }
    __syncthreads();
#pragma unroll
    for (int ct = 0; ct < 2; ++ct) {
      f16x8 ah = *reinterpret_cast<const f16x8*>(&Wsh[co0 + ct * 16 + l15][quad * 8]);
      f16x8 al = *reinterpret_cast<const f16x8*>(&Wsl[co0 + ct * 16 + l15][quad * 8]);
#pragma unroll
      for (int pt = 0; pt < 2; ++pt) {
        f16x8 bh = *reinterpret_cast<const f16x8*>(&Xsh[pt * 16 + l15][kc * 32 + quad * 8]);
        f16x8 bl = *reinterpret_cast<const f16x8*>(&Xsl[pt * 16 + l15][kc * 32 + quad * 8]);
        acc[ct][pt] = __builtin_amdgcn_mfma_f32_16x16x32_f16(ah, bl, acc[ct][pt], 0, 0, 0);
        acc[ct][pt] = __builtin_amdgcn_mfma_f32_16x16x32_f16(al, bh, acc[ct][pt], 0, 0, 0);
        acc[ct][pt] = __builtin_amdgcn_mfma_f32_16x16x32_f16(ah, bh, acc[ct][pt], 0, 0, 0);
      }
    }
  }

  float sp[2][4] = {{0.f}}, sp2[2][4] = {{0.f}};
#pragma unroll
  for (int ct = 0; ct < 2; ++ct)
#pragma unroll
    for (int pt = 0; pt < 2; ++pt) {
      int p = p0 + pt * 16 + l15;
      if (p < BB * NN) {
        int b = p / NN, n = p % NN;
#pragma unroll
        for (int r = 0; r < 4; ++r) {
          int co = co0 + ct * 16 + quad * 4 + r;
          float v = acc[ct][pt][r] + bias[co];
          Y[(b * 128 + co) * NN + n] = v;
          sp[ct][r] += v;
          sp2[ct][r] += v * v;
        }
      }
    }
#pragma unroll
  for (int ct = 0; ct < 2; ++ct)
#pragma unroll
    for (int r = 0; r < 4; ++r)
#pragma unroll
      for (int d = 1; d <= 8; d <<= 1) {
        sp[ct][r] += __shfl_xor(sp[ct][r], d);
        sp2[ct][r] += __shfl_xor(sp2[ct][r], d);
      }
  if (l15 == 0) {
#pragma unroll
    for (int ct = 0; ct < 2; ++ct)
#pragma unroll
      for (int r = 0; r < 4; ++r) {
        int co = co0 + ct * 16 + quad * 4 + r;
        atomicAdd(&osums[co], sp[ct][r]);
        atomicAdd(&osums[128 + co], sp2[ct][r]);
      }
  }
}

// ---------------- MFMA conv: QKV, pre-converted W, bn+relu input
__launch_bounds__(256)
__global__ void conv_mfma_qkv(const float* __restrict__ Yp, const float* __restrict__ psums,
                              const float* __restrict__ pg, const float* __restrict__ pbeta,
                              const f16* __restrict__ WCV,
                              const float* __restrict__ qb, const float* __restrict__ kb,
                              const float* __restrict__ vb,
                              f16* __restrict__ Qh, f16* __restrict__ Ql,
                              f16* __restrict__ Kh, f16* __restrict__ Kl,
                              f16* __restrict__ Vh, f16* __restrict__ Vl) {
  __shared__ f16 Xsh[32][136], Xsl[32][136];
  __shared__ f16 Wsh[128][40], Wsl[128][40];
  __shared__ float bnsc[128], bnsh[128];
  const int tid = threadIdx.x;
  const int p0 = blockIdx.x * 32;
  const int sel = blockIdx.y;
  const int w = tid >> 6, lane = tid & 63, quad = lane >> 4, l15 = lane & 15;
  const int co0 = w * 32;
  const f16* Wh = WCV + (2 + sel * 2) * 16384;
  const f16* Wl = Wh + 16384;
  const float* bias = (sel == 0) ? qb : (sel == 1) ? kb : vb;

  for (int c = tid; c < 128; c += 256) {
    float s = psums[c], s2 = psums[128 + c];
    float mean = s * INV_CNT;
    float var = s2 * INV_CNT - mean * mean;
    float sc = pg[c] * rsqrtf(var + BN_EPS);
    bnsc[c] = sc;
    bnsh[c] = pbeta[c] - mean * sc;
  }
  __syncthreads();

  for (int idx = tid; idx < 512; idx += 256) {
    int ci = (idx >> 5) * 8, j = idx & 31;
    int p = p0 + j;
    if (p >= BB * NN) p = BB * NN - 1;
    int b = p / NN, n = p % NN;
    f16x8 hv, lv;
#pragma unroll
    for (int t = 0; t < 8; ++t) {
      float v = Yp[(b * 128 + ci + t) * NN + n];
      v = v * bnsc[ci + t] + bnsh[ci + t];
      v = v > 0.f ? v : 0.f;
      f16 h = (f16)v;
      hv[t] = h;
      lv[t] = (f16)(v - (float)h);
    }
    *reinterpret_cast<f16x8*>(&Xsh[j][ci]) = hv;
    *reinterpret_cast<f16x8*>(&Xsl[j][ci]) = lv;
  }

  f32x4 acc[2][2];
#pragma unroll
  for (int ct = 0; ct < 2; ++ct)
#pragma unroll
    for (int pt = 0; pt < 2; ++pt) acc[ct][pt] = (f32x4){0.f, 0.f, 0.f, 0.f};

  for (int kc = 0; kc < 4; ++kc) {
    __syncthreads();
    for (int idx = tid; idx < 512; idx += 256) {
      int co = idx >> 2, ks = idx & 3;
      int off = co * 128 + kc * 32 + ks * 8;
      *reinterpret_cast<uint4*>(&Wsh[co][ks * 8]) =
          *reinterpret_cast<const uint4*>(Wh + off);
      *reinterpret_cast<uint4*>(&Wsl[co][ks * 8]) =
          *reinterpret_cast<const uint4*>(Wl + off);
    }
    __syncthreads();
#pragma unroll
    for (int ct = 0; ct < 2; ++ct) {
      f16x8 ah = *reinterpret_cast<const f16x8*>(&Wsh[co0 + ct * 16 + l15][quad * 8]);
      f16x8 al = *reinterpret_cast<const f16x8*>(&Wsl[co0 + ct * 16 + l15][quad * 8]);
#pragma unroll
      for (int pt = 0; pt < 2; ++pt) {
        f16x8 bh = *reinterpret_cast<const f16x8*>(&Xsh[pt * 16 + l15][kc * 32 + quad * 8]);
        f16x8 bl = *reinterpret_cast<const f16x8*>(&Xsl[pt * 16 + l15][kc * 32 + quad * 8]);
        acc[ct][pt] = __builtin_amdgcn_mfma_f32_16x16x32_f16(ah, bl, acc[ct][pt], 0, 0, 0);
        acc[ct][pt] = __builtin_amdgcn_mfma_f32_16x16x32_f16(al, bh, acc[ct][pt], 0, 0, 0);
        acc[ct][pt] = __builtin_amdgcn_mfma_f32_16x16x32_f16(ah, bh, acc[ct][pt], 0, 0, 0);
      }
    }
  }

#pragma unroll
  for (int ct = 0; ct < 2; ++ct)
#pragma unroll
    for (int pt = 0; pt < 2; ++pt) {
      int p = p0 + pt * 16 + l15;
      if (p < BB * NN) {
        int b = p / NN, n = p % NN;
#pragma unroll
        for (int r = 0; r < 4; ++r) {
          int co = co0 + ct * 16 + quad * 4 + r;
          float v = acc[ct][pt][r] + bias[co];
          f16 h = (f16)v;
          f16 lo = (f16)(v - (float)h);
          if (sel == 0) {
            size_t o = (size_t)(b * NN + n) * CC + co;
            Qh[o] = h; Ql[o] = lo;
          } else if (sel == 1) {
            size_t o = (size_t)(b * NN + n) * CC + co;
            Kh[o] = h; Kl[o] = lo;
          } else {
            size_t o = (size_t)(b * CC + co) * NN + n;
            Vh[o] = h; Vl[o] = lo;
          }
        }
      }
    }
}

// ---------------- generic VALU conv (r14 proven), NP points per block.
template <int CIN, int COUT, int NP, int MODE, int CSPLIT, int BNIN, int STATS>
__launch_bounds__(256)
__global__ void conv_k(const float* __restrict__ in, float* __restrict__ out,
                       const float* __restrict__ W, const float* __restrict__ bias,
                       const float* __restrict__ res,
                       const float* __restrict__ isums, const float* __restrict__ ig,
                       const float* __restrict__ ibeta,
                       const float* __restrict__ rsums, const float* __restrict__ rg,
                       const float* __restrict__ rbeta, float* __restrict__ osums) {
  constexpr int COB = COUT / CSPLIT;
  constexpr int CH = (CIN > 64) ? 64 : CIN;
  constexpr int PG = NP / 4;
  constexpr int KPT = COB * PG / 256;
  constexpr int XROW = (NP == 16) ? 20 : 32;
  __shared__ alignas(16) float Xs[CIN][XROW];
  __shared__ float Ws[COB][CH + 1];
  __shared__ float bnsc[BNIN ? CIN : 1], bnsh[BNIN ? CIN : 1];
  const int tid = threadIdx.x;
  const int p0 = blockIdx.x * NP;
  const int co0 = blockIdx.y * COB;

  if (BNIN) {
    for (int c = tid; c < CIN; c += 256) {
      float s = isums[c], s2 = isums[CIN + c];
      float mean = s * INV_CNT;
      float var = s2 * INV_CNT - mean * mean;
      float sc = ig[c] * rsqrtf(var + BN_EPS);
      bnsc[c] = sc;
      bnsh[c] = ibeta[c] - mean * sc;
    }
    __syncthreads();
  }

  for (int idx = tid; idx < CIN * NP; idx += 256) {
    int ci = idx / NP, j = idx % NP;
    int p = p0 + j;
    float v = 0.f;
    if (p < BB * NN) {
      int b = p / NN, n = p % NN;
      v = in[(b * CIN + ci) * NN + n];
      if (BNIN) {
        v = v * bnsc[ci] + bnsh[ci];
        v = v > 0.f ? v : 0.f;
      }
    }
    Xs[ci][j] = v;
  }

  const int nb = (tid % PG) * 4;
  const int cb = (tid / PG) * KPT;

  float acc[KPT][4];
#pragma unroll
  for (int k = 0; k < KPT; ++k)
#pragma unroll
    for (int j = 0; j < 4; ++j) acc[k][j] = 0.f;

  for (int c0 = 0; c0 < CIN; c0 += CH) {
    __syncthreads();
    for (int idx = tid; idx < COB * CH; idx += 256) {
      int co = idx / CH, cc = idx % CH;
      Ws[co][cc] = W[(co0 + co) * CIN + c0 + cc];
    }
    __syncthreads();
#pragma unroll 4
    for (int cc = 0; cc < CH; ++cc) {
      float4 xv = *reinterpret_cast<const float4*>(&Xs[c0 + cc][nb]);
#pragma unroll
      for (int k = 0; k < KPT; ++k) {
        float w = Ws[cb + k][cc];
        acc[k][0] += w * xv.x;
        acc[k][1] += w * xv.y;
        acc[k][2] += w * xv.z;
        acc[k][3] += w * xv.w;
      }
    }
  }

#pragma unroll
  for (int k = 0; k < KPT; ++k) {
    int co = co0 + cb + k;
    float bv = bias[co];
    float rsc = 0.f, rsh = 0.f;
    if (MODE == 3) {
      float s = rsums[co], s2 = rsums[COUT + co];
      float mean = s * INV_CNT;
      float var = s2 * INV_CNT - mean * mean;
      rsc = rg[co] * rsqrtf(var + BN_EPS);
      rsh = rbeta[co] - mean * rsc;
    }
    float sp = 0.f, sp2 = 0.f;
#pragma unroll
    for (int j = 0; j < 4; ++j) {
      int p = p0 + nb + j;
      if (p < BB * NN) {
        int b = p / NN, n = p % NN;
        int o = (b * COUT + co) * NN + n;
        float v = acc[k][j] + bv;
        if (MODE == 3) {
          float rr = res[o] * rsc + rsh;
          v += (rr > 0.f ? rr : 0.f);
        }
        out[o] = v;
        if (STATS) {
          sp += v;
          sp2 += v * v;
        }
      }
    }
    if (STATS) {
#pragma unroll
      for (int d = 1; d < PG; d <<= 1) {
        sp += __shfl_xor(sp, d);
        sp2 += __shfl_xor(sp2, d);
      }
      if ((tid & (PG - 1)) == 0) {
        atomicAdd(&osums[co], sp);
        atomicAdd(&osums[COUT + co], sp2);
      }
    }
  }
}

// ---------------- full-MFMA attention: 128 q/block, qp in LDS, 2 blocks/CU (r17)
__launch_bounds__(512, 4)
__global__ void attn_mf9(const f16* __restrict__ Qhp, const f16* __restrict__ Qlp,
                         const f16* __restrict__ Khp, const f16* __restrict__ Klp,
                         const f16* __restrict__ Vhp, const f16* __restrict__ Vlp,
                         const float* __restrict__ srcp, const float* __restrict__ tgtp,
                         float* __restrict__ pacc, float* __restrict__ pm,
                         float* __restrict__ pl, int chunk) {
  const int b = blockIdx.z;
  const int q0 = blockIdx.x * 128;
  const int s = blockIdx.y;
  const int cs = s * chunk;
  const int ce = min(cs + chunk, NN);
  const int tid = threadIdx.x;
  const int w = tid >> 6, lane = tid & 63, quad = lane >> 4, l15 = lane & 15;

  __shared__ f16 Ksh[32][136], Ksl[32][136];
  __shared__ f16 Vsh[128][40], Vsl[128][40];
  __shared__ f16 Ps[8][16][40];
  __shared__ float kps[6][36];
  __shared__ float qps[8][16][6];

  for (int t = tid; t < 768; t += 512) {
    int w2 = t / 96, rem = t % 96, row = rem / 6, d = rem % 6;
    int o = q0 + w2 * 16 + row;
    if (o >= NN) o = NN - 1;
    qps[w2][row][d] = (d < 3) ? srcp[(b * NN + o) * 3 + d] : tgtp[(b * NN + o) * 3 + d - 3];
  }

  f16x8 qh[4], ql[4];
  const int orow = q0 + w * 16;
  {
    int o = orow + l15;
    if (o >= NN) o = NN - 1;
    size_t base = (size_t)(b * NN + o) * CC + quad * 8;
#pragma unroll
    for (int cc = 0; cc < 4; ++cc) {
      qh[cc] = *reinterpret_cast<const f16x8*>(Qhp + base + cc * 32);
      ql[cc] = *reinterpret_cast<const f16x8*>(Qlp + base + cc * 32);
    }
  }

  float m[4], l[4];
#pragma unroll
  for (int r = 0; r < 4; ++r) {
    m[r] = -1e30f;
    l[r] = 0.f;
  }
  f32x4 acco[8];
#pragma unroll
  for (int t = 0; t < 8; ++t) acco[t] = (f32x4){0.f, 0.f, 0.f, 0.f};

  const int NT = (ce - cs + 31) >> 5;
  for (int it = 0; it < NT; ++it) {
    const int kk0 = cs + it * 32;
    __syncthreads();
    for (int t = tid; t < 1024; t += 512) {
      int plane = t >> 9, row = (t >> 4) & 31, cu = t & 15;
      int kr = kk0 + row;
      if (kr >= NN) kr = NN - 1;
      const f16* src = (plane ? Klp : Khp) + (size_t)(b * NN + kr) * CC + cu * 8;
      uint4 v = *reinterpret_cast<const uint4*>(src);
      f16* dst = plane ? &Ksl[row][cu * 8] : &Ksh[row][cu * 8];
      *reinterpret_cast<uint4*>(dst) = v;
    }
    for (int t = tid; t < 1024; t += 512) {
      int plane = t >> 9, c = (t >> 2) & 127, iu = t & 3;
      int kb = kk0 + iu * 8;
      if (kb > NN - 8) kb = NN - 8;
      const f16* src = (plane ? Vlp : Vhp) + (size_t)(b * CC + c) * NN + kb;
      uint4 v = *reinterpret_cast<const uint4*>(src);
      f16* dst = plane ? &Vsl[c][iu * 8] : &Vsh[c][iu * 8];
      *reinterpret_cast<uint4*>(dst) = v;
    }
    if (tid < 192) {
      int d = tid >> 5, i = tid & 31;
      int ig = kk0 + i;
      if (ig >= NN) ig = NN - 1;
      kps[d][i] = (d < 3) ? srcp[(b * NN + ig) * 3 + d] : tgtp[(b * NN + ig) * 3 + d - 3];
    }
    __syncthreads();

    f32x4 accs[2];
#pragma unroll
    for (int k4 = 0; k4 < 2; ++k4) accs[k4] = (f32x4){0.f, 0.f, 0.f, 0.f};
#pragma unroll
    for (int cc = 0; cc < 4; ++cc) {
#pragma unroll
      for (int k4 = 0; k4 < 2; ++k4) {
        f16x8 bh = *reinterpret_cast<const f16x8*>(&Ksh[k4 * 16 + l15][cc * 32 + quad * 8]);
        f16x8 bl = *reinterpret_cast<const f16x8*>(&Ksl[k4 * 16 + l15][cc * 32 + quad * 8]);
        accs[k4] = __builtin_amdgcn_mfma_f32_16x16x32_f16(qh[cc], bl, accs[k4], 0, 0, 0);
        accs[k4] = __builtin_amdgcn_mfma_f32_16x16x32_f16(ql[cc], bh, accs[k4], 0, 0, 0);
        accs[k4] = __builtin_amdgcn_mfma_f32_16x16x32_f16(qh[cc], bh, accs[k4], 0, 0, 0);
      }
    }

    float sv[2][4];
#pragma unroll
    for (int r = 0; r < 4; ++r) {
      const float* qp6 = qps[w][quad * 4 + r];
      float q0v = qp6[0], q1v = qp6[1], q2v = qp6[2];
      float q3v = qp6[3], q4v = qp6[4], q5v = qp6[5];
#pragma unroll
      for (int k4 = 0; k4 < 2; ++k4) {
        int iloc = k4 * 16 + l15;
        int ig = kk0 + iloc;
        float dx = q0v - kps[0][iloc], dy = q1v - kps[1][iloc], dz = q2v - kps[2][iloc];
        float ds2 = dx * dx + dy * dy + dz * dz;
        float ex = q3v - kps[3][iloc], ey = q4v - kps[4][iloc], ez = q5v - kps[5][iloc];
        float dt2 = ex * ex + ey * ey + ez * ez;
        float d2 = ds2 + dt2 - 2.f * sqrtf(ds2 * dt2);
        float gg = 1.f - d2;
        gg = gg > 0.f ? gg : 0.f;
        float val = accs[k4][r] * (ATT_SCALE * gg);
        sv[k4][r] = (ig < ce) ? val : -1e30f;
      }
    }

    float tmax[4];
#pragma unroll
    for (int r = 0; r < 4; ++r) tmax[r] = fmaxf(sv[0][r], sv[1][r]);
#pragma unroll
    for (int d = 1; d <= 8; d <<= 1)
#pragma unroll
      for (int r = 0; r < 4; ++r) tmax[r] = fmaxf(tmax[r], __shfl_xor(tmax[r], d));

    float alpha[4], ps[4];
    f16 pf[2][4];
#pragma unroll
    for (int r = 0; r < 4; ++r) {
      float mn = fmaxf(m[r], tmax[r]);
      alpha[r] = __expf(m[r] - mn);
      m[r] = mn;
      pf[0][r] = (f16)__expf(sv[0][r] - mn);
      pf[1][r] = (f16)__expf(sv[1][r] - mn);
      ps[r] = (float)pf[0][r] + (float)pf[1][r];
    }
#pragma unroll
    for (int d = 1; d <= 8; d <<= 1)
#pragma unroll
      for (int r = 0; r < 4; ++r) ps[r] += __shfl_xor(ps[r], d);
#pragma unroll
    for (int r = 0; r < 4; ++r) {
      l[r] = l[r] * alpha[r] + ps[r];
#pragma unroll
      for (int t = 0; t < 8; ++t) acco[t][r] *= alpha[r];
    }
#pragma unroll
    for (int r = 0; r < 4; ++r) {
      Ps[w][quad * 4 + r][l15] = pf[0][r];
      Ps[w][quad * 4 + r][16 + l15] = pf[1][r];
    }
    __syncthreads();

    {
      f16x8 af = *reinterpret_cast<const f16x8*>(&Ps[w][l15][quad * 8]);
#pragma unroll
      for (int t = 0; t < 8; ++t) {
        f16x8 vh = *reinterpret_cast<const f16x8*>(&Vsh[t * 16 + l15][quad * 8]);
        f16x8 vl = *reinterpret_cast<const f16x8*>(&Vsl[t * 16 + l15][quad * 8]);
        acco[t] = __builtin_amdgcn_mfma_f32_16x16x32_f16(af, vl, acco[t], 0, 0, 0);
        acco[t] = __builtin_amdgcn_mfma_f32_16x16x32_f16(af, vh, acco[t], 0, 0, 0);
      }
    }
  }

  const int pidx = s * BB + b;
  if (l15 == 0) {
#pragma unroll
    for (int r = 0; r < 4; ++r) {
      int o = orow + quad * 4 + r;
      if (o < NN) {
        pm[pidx * NN + o] = m[r];
        pl[pidx * NN + o] = l[r];
      }
    }
  }
#pragma unroll
  for (int r = 0; r < 4; ++r) {
    int o = orow + quad * 4 + r;
    if (o < NN) {
      size_t base2 = ((size_t)pidx * NN + o) * CC;
#pragma unroll
      for (int t = 0; t < 8; ++t) pacc[base2 + t * 16 + l15] = acco[t][r];
    }
  }
}

// ---------------- m1 conv (16-pt tiles) with fused K-split combine + stats (r14)
__launch_bounds__(256)
__global__ void conv_m1(const float* __restrict__ pacc, const float* __restrict__ pm,
                        const float* __restrict__ pl, float* __restrict__ out,
                        const float* __restrict__ W, const float* __restrict__ bias,
                        float* __restrict__ osums, int ksplit) {
  __shared__ alignas(16) float Xs[128][20];
  __shared__ float Ws[64][65];
  __shared__ float Es[16][17];
  __shared__ float Li[16];
  const int tid = threadIdx.x;
  const int p0 = blockIdx.x * 16;

  if (tid < 16) {
    int p = p0 + tid;
    float Lv = 1.f;
    if (p < BB * NN) {
      int b = p / NN, o = p % NN;
      float M = -1e30f;
      for (int s = 0; s < ksplit; ++s) M = fmaxf(M, pm[(s * BB + b) * NN + o]);
      Lv = 0.f;
      for (int s = 0; s < ksplit; ++s) {
        int pi = s * BB + b;
        float e = __expf(pm[pi * NN + o] - M);
        Es[tid][s] = e;
        Lv += pl[pi * NN + o] * e;
      }
    } else {
      for (int s = 0; s < ksplit; ++s) Es[tid][s] = 0.f;
    }
    Li[tid] = 1.f / Lv;
  }
  __syncthreads();

  for (int idx = tid; idx < 512; idx += 256) {
    int j = idx >> 5, c4 = (idx & 31) * 4;
    int p = p0 + j;
    float4 a = {0.f, 0.f, 0.f, 0.f};
    if (p < BB * NN) {
      int b = p / NN, o = p % NN;
      for (int s = 0; s < ksplit; ++s) {
        float e = Es[j][s];
        const float4 pv = *reinterpret_cast<const float4*>(
            &pacc[((size_t)(s * BB + b) * NN + o) * CC + c4]);
        a.x += pv.x * e;
        a.y += pv.y * e;
        a.z += pv.z * e;
        a.w += pv.w * e;
      }
      float inv = Li[j];
      a.x *= inv; a.y *= inv; a.z *= inv; a.w *= inv;
    }
    Xs[c4][j] = a.x;
    Xs[c4 + 1][j] = a.y;
    Xs[c4 + 2][j] = a.z;
    Xs[c4 + 3][j] = a.w;
  }

  const int nb = (tid & 3) * 4;
  const int co = tid >> 2;
  float acc[4] = {0.f, 0.f, 0.f, 0.f};

  for (int c0 = 0; c0 < 128; c0 += 64) {
    __syncthreads();
    for (int idx = tid; idx < 64 * 64; idx += 256) {
      int cr = idx >> 6, cc = idx & 63;
      Ws[cr][cc] = W[cr * 128 + c0 + cc];
    }
    __syncthreads();
#pragma unroll 4
    for (int cc = 0; cc < 64; ++cc) {
      float4 xv = *reinterpret_cast<const float4*>(&Xs[c0 + cc][nb]);
      float w = Ws[co][cc];
      acc[0] += w * xv.x;
      acc[1] += w * xv.y;
      acc[2] += w * xv.z;
      acc[3] += w * xv.w;
    }
  }

  {
    float bv = bias[co];
    float sp = 0.f, sp2 = 0.f;
#pragma unroll
    for (int j = 0; j < 4; ++j) {
      int p = p0 + nb + j;
      if (p < BB * NN) {
        int b = p / NN, n = p % NN;
        float v = acc[j] + bv;
        out[(b * 64 + co) * NN + n] = v;
        sp += v;
        sp2 += v * v;
      }
    }
    sp += __shfl_xor(sp, 1);
    sp2 += __shfl_xor(sp2, 1);
    sp += __shfl_xor(sp, 2);
    sp2 += __shfl_xor(sp2, 2);
    if ((tid & 3) == 0) {
      atomicAdd(&osums[co], sp);
      atomicAdd(&osums[64 + co], sp2);
    }
  }
}

// ---------------- fused head (proven)
__launch_bounds__(256)
__global__ void head_all(const float* __restrict__ Xg,
                         const float* __restrict__ c1W, const float* __restrict__ c1b,
                         const float* __restrict__ c2W, const float* __restrict__ c2b,
                         const float* __restrict__ c3W, const float* __restrict__ c3b,
                         float* __restrict__ out) {
  __shared__ float Xs[128][33];
  __shared__ float W1[32][129];
  __shared__ float W2[32][33];
  __shared__ float Hs[32][33], H2s[32][33];
  __shared__ float Inv[32];
  const int tid = threadIdx.x;
  const int p0 = blockIdx.x * 32;
  const int j = tid >> 3, sub = tid & 7;

  for (int idx = tid; idx < 128 * 32; idx += 256) {
    int ci = idx >> 5, jj = idx & 31;
    int p = p0 + jj;
    float v = 0.f;
    if (p < BB * NN) {
      int b = p / NN, n = p % NN;
      v = Xg[(b * 128 + ci) * NN + n];
    }
    Xs[ci][jj] = v;
  }
  for (int idx = tid; idx < 32 * 128; idx += 256) {
    W1[idx >> 7][idx & 127] = c1W[idx];
  }
  for (int idx = tid; idx < 32 * 32; idx += 256) {
    W2[idx >> 5][idx & 31] = c2W[idx];
  }
  __syncthreads();

  {
    float h1v[4];
#pragma unroll
    for (int k = 0; k < 4; ++k) h1v[k] = c1b[sub * 4 + k];
    for (int ci = 0; ci < 128; ++ci) {
      float xv = Xs[ci][j];
#pragma unroll
      for (int k = 0; k < 4; ++k) h1v[k] += W1[sub * 4 + k][ci] * xv;
    }
#pragma unroll
    for (int k = 0; k < 4; ++k) Hs[j][sub * 4 + k] = h1v[k] > 0.f ? h1v[k] : 0.f;
  }
  __syncthreads();
  {
    float h2v[4];
#pragma unroll
    for (int k = 0; k < 4; ++k) h2v[k] = c2b[sub * 4 + k];
#pragma unroll
    for (int cc = 0; cc < 32; ++cc) {
      float hv = Hs[j][cc];
#pragma unroll
      for (int k = 0; k < 4; ++k) h2v[k] += W2[sub * 4 + k][cc] * hv;
    }
#pragma unroll
    for (int k = 0; k < 4; ++k) H2s[j][sub * 4 + k] = h2v[k] > 0.f ? h2v[k] : 0.f;
  }
  __syncthreads();

  float ssp = 0.f;
#pragma unroll
  for (int k = 0; k < 16; ++k) {
    float v = Xs[sub + 8 * k][j];
    ssp += v * v;
  }
  ssp += __shfl_xor(ssp, 1);
  ssp += __shfl_xor(ssp, 2);
  ssp += __shfl_xor(ssp, 4);

  if (sub == 0) {
    int p = p0 + j;
    if (p < BB * NN) {
      float conf = c3b[0];
#pragma unroll
      for (int c = 0; c < 32; ++c) conf += c3W[c] * H2s[j][c];
      out[p] = conf;
    }
    float nrm = sqrtf(ssp);
    nrm = nrm > 1e-12f ? nrm : 1e-12f;
    Inv[j] = 1.f / nrm;
  }
  __syncthreads();

  for (int idx = tid; idx < 128 * 32; idx += 256) {
    int c = idx >> 5, jj = idx & 31;
    int p = p0 + jj;
    if (p < BB * NN) {
      int b = p / NN, n = p % NN;
      out[BB * NN + (b * 128 + c) * NN + n] = Xs[c][jj] * Inv[jj];
    }
  }
}

extern "C" void kernel_launch(void* const* d_in, const int* in_sizes, int n_in,
                              void* d_out, int out_size, void* d_ws, size_t ws_size,
                              hipStream_t stream) {
  const float* corr = (const float*)d_in[0];
  const float* srcp = (const float*)d_in[1];
  const float* tgtp = (const float*)d_in[2];
  const float* initW = (const float*)d_in[3];
  const float* initb = (const float*)d_in[4];
  const float* pcnW = (const float*)d_in[5];
  const float* pcnb = (const float*)d_in[6];
  const float* pcng = (const float*)d_in[7];
  const float* pcnbeta = (const float*)d_in[8];
  const float* qW = (const float*)d_in[9];
  const float* qb = (const float*)d_in[10];
  const float* kW = (const float*)d_in[11];
  const float* kb = (const float*)d_in[12];
  const float* vW = (const float*)d_in[13];
  const float* vb = (const float*)d_in[14];
  const float* m1W = (const float*)d_in[15];
  const float* m1b = (const float*)d_in[16];
  const float* m1g = (const float*)d_in[17];
  const float* m1beta = (const float*)d_in[18];
  const float* m2W = (const float*)d_in[19];
  const float* m2b = (const float*)d_in[20];
  const float* m2g = (const float*)d_in[21];
  const float* m2beta = (const float*)d_in[22];
  const float* m3W = (const float*)d_in[23];
  const float* m3b = (const float*)d_in[24];
  const float* c1W = (const float*)d_in[25];
  const float* c1b = (const float*)d_in[26];
  const float* c2W = (const float*)d_in[27];
  const float* c2b = (const float*)d_in[28];
  const float* c3W = (const float*)d_in[29];
  const float* c3b = (const float*)d_in[30];

  const int FEAT = BB * CC * NN;   // 768000
  const int PLANE = FEAT / 2;
  float* ws = (float*)d_ws;
  float* X = ws;
  float* Y = X + FEAT;
  float* QhF = Y + FEAT;
  float* QlF = QhF + PLANE;
  float* KhF = QlF + PLANE;
  float* KlF = KhF + PLANE;
  float* VhF = KlF + PLANE;
  float* VlF = VhF + PLANE;
  float* SB = VlF + PLANE;            // stats (3072 floats)
  float* WCVf = SB + 3072;            // all-layer weight planes (393216 floats)
  float* pacc = WCVf + LAYERS * 65536;
  f16* Qh = (f16*)QhF;
  f16* Ql = (f16*)QlF;
  f16* Kh = (f16*)KhF;
  f16* Kl = (f16*)KlF;
  f16* Vh = (f16*)VhF;
  f16* Vl = (f16*)VlF;
  f16* WCV = (f16*)WCVf;
  float* T1 = QhF;
  float* T2 = KhF;

  const size_t base_f = (size_t)(2 * FEAT + 6 * PLANE + 3072 + LAYERS * 65536);
  const size_t per_f = (size_t)BB * NN * CC + 2 * (size_t)BB * NN;
  int ksplit = 16;
  while (ksplit > 1 && (base_f + (size_t)ksplit * per_f) * 4 > ws_size) ksplit >>= 1;
  const int chunk = (((NN + ksplit - 1) / ksplit) + 7) & ~7;
  float* pm = pacc + (size_t)ksplit * BB * NN * CC;
  float* pl = pm + (size_t)ksplit * BB * NN;

  dim3 blk(256);
  const int PT32 = (BB * NN + 31) / 32;  // 188
  const int PT16 = (BB * NN + 15) / 16;  // 375
  const int G_FEAT = (FEAT + 255) / 256;

  hipMemsetAsync(SB, 0, 3072 * sizeof(float), stream);
  convert_w_all<<<(LAYERS * 4 * 16384 + 255) / 256, blk, 0, stream>>>(
      pcnW, qW, kW, vW, WCV);
  init_conv<<<G_FEAT, blk, 0, stream>>>(corr, initW, initb, X);

  for (int i = 0; i < LAYERS; ++i) {
    float* pcnS = SB + i * 512;
    float* m1S = pcnS + 256;
    float* m2S = m1S + 128;
    const f16* WL = WCV + (size_t)i * 131072;
    conv_mfma_pcn<<<PT32, blk, 0, stream>>>(X, Y, WL, pcnb + i * 128, pcnS);
    conv_mfma_qkv<<<dim3(PT32, 3), blk, 0, stream>>>(
        Y, pcnS, pcng + i * 128, pcnbeta + i * 128, WL,
        qb + i * 128, kb + i * 128, vb + i * 128, Qh, Ql, Kh, Kl, Vh, Vl);
    attn_mf9<<<dim3((NN + 127) / 128, ksplit, BB), dim3(512), 0, stream>>>(
        Qh, Ql, Kh, Kl, Vh, Vl, srcp, tgtp, pacc, pm, pl, chunk);
    conv_m1<<<PT16, blk, 0, stream>>>(pacc, pm, pl, T1, m1W + i * 8192, m1b + i * 64,
                                      m1S, ksplit);
    conv_k<64, 64, 16, 0, 1, 1, 1><<<dim3(PT16, 1), blk, 0, stream>>>(
        T1, T2, m2W + i * 4096, m2b + i * 64, nullptr,
        m1S, m1g + i * 64, m1beta + i * 64, nullptr, nullptr, nullptr, m2S);
    conv_k<64, 128, 16, 3, 2, 1, 0><<<dim3(PT16, 2), blk, 0, stream>>>(
        T2, X, m3W + i * 8192, m3b + i * 128, Y,
        m2S, m2g + i * 64, m2beta + i * 64, pcnS, pcng + i * 128, pcnbeta + i * 128,
        nullptr);
  }

  head_all<<<PT32, blk, 0, stream>>>(X, c1W, c1b, c2W, c2b, c3W, c3b, (float*)d_out);
}